// Round 1
// baseline (11079.730 us; speedup 1.0000x reference)
//
#include <hip/hip_runtime.h>
#include <hip/hip_fp16.h>
#include <math.h>
#include <stdint.h>

// MobiusGRU T=256 B=64 D=H=512, 2 layers.
// R8 = k-split scan. 4 WGs/row each own a 128-wide K-SLICE of Whh (not output
// columns). Per step only TWO cross-WG exchange rounds (phase-A partials,
// phase-B partials); all norms/reduces and the h update are computed locally
// (redundantly) by every WG, so the h and wv broadcasts and the S1/S3/S4
// cross-WG reduces of R7 disappear. 5 barriers/step (was 10), 2 remote rounds
// (was 5). h element lives in a register per thread. Fence-free tagged
// {tag,value} u64 relaxed agent atomics as before; rounds are interlocked so
// overwrites are ordered behind all readers. Layers share comm buffers via
// disjoint tag ranges (L1: 1..256, L2: 257..512) -- replay-safe because every
// slot is rewritten every step.

#define T_  256
#define B_  64
#define H_  512
#define G3_ 1536
#define EPSF 1e-15f
#define CLIPF (1.0f - 1e-5f)
#define SCOPE_AGENT __HIP_MEMORY_SCOPE_AGENT

typedef _Float16 v2h __attribute__((ext_vector_type(2)));

__device__ __forceinline__ float fdot2_(unsigned int w, unsigned int h, float c){
#if __has_builtin(__builtin_amdgcn_fdot2)
  return __builtin_amdgcn_fdot2(__builtin_bit_cast(v2h, w), __builtin_bit_cast(v2h, h), c, false);
#else
  const __half2 wh = __builtin_bit_cast(__half2, w);
  const __half2 hh = __builtin_bit_cast(__half2, h);
  return c + __low2float(wh)*__low2float(hh) + __high2float(wh)*__high2float(hh);
#endif
}

__device__ __forceinline__ float artanh_c(float x){
  x = fminf(fmaxf(x, -CLIPF), CLIPF);
  return 0.5f * logf((1.0f + x) / (1.0f - x));
}
__device__ __forceinline__ float sigmoidf_(float x){ return 1.0f/(1.0f+expf(-x)); }
__device__ __forceinline__ float hsum4(float4 v){ return (v.x+v.y)+(v.z+v.w); }
__device__ __forceinline__ float sum8(const float* r){
  const float4* p = (const float4*)r;
  return hsum4(p[0]) + hsum4(p[1]);
}

// fence-free tagged post (relaxed agent atomic: no cache inv/wb)
__device__ __forceinline__ void postf(unsigned long long* p, float x, unsigned tag){
  unsigned long long v = ((unsigned long long)tag << 32) |
                         (unsigned long long)__float_as_uint(x);
  __hip_atomic_store(p, v, __ATOMIC_RELAXED, SCOPE_AGENT);
}

// reduce NS values across the wave; lane0 stores red[s*8 + wave] (8 waves)
template<int NS>
__device__ __forceinline__ void wave_reduce_store(float (&v)[NS], float* red, int tid){
  #pragma unroll
  for (int off = 32; off > 0; off >>= 1)
    #pragma unroll
    for (int s = 0; s < NS; s++) v[s] += __shfl_xor(v[s], off);
  if ((tid & 63) == 0)
    #pragma unroll
    for (int s = 0; s < NS; s++) red[s*8 + (tid >> 6)] = v[s];
}

// full gate evaluation: mobius_matvec scale + 2x mobius_add + logmap0 + sigmoid
__device__ __forceinline__ float gate_val(float a, float y, float bv,
    float A2, float AY, float Y2, float AB, float YB, float B2,
    float xn, float art_h){
  const float mraw = sqrtf(A2);
  const float mnc = fmaxf(mraw, EPSF);
  const float alpha = (mraw <= EPSF) ? 0.f : (tanhf(mnc/xn*art_h)/mnc);
  const float X2 = alpha*alpha*A2, XY = alpha*AY, XB = alpha*AB;
  const float cA1 = 1.f + 2.f*XY + Y2, cB1 = 1.f - X2;
  const float den1 = fmaxf(1.f + 2.f*XY + X2*Y2, EPSF), id1 = 1.f/den1;
  const float T2 = fmaxf((cA1*cA1*X2 + 2.f*cA1*cB1*XY + cB1*cB1*Y2)*id1*id1, 0.f);
  const float TB = (cA1*XB + cB1*YB)*id1;
  const float cA2 = 1.f + 2.f*TB + B2, cB2 = 1.f - T2;
  const float den2 = fmaxf(1.f + 2.f*TB + T2*B2, EPSF), id2 = 1.f/den2;
  const float U2 = fmaxf((cA2*cA2*T2 + 2.f*cA2*cB2*TB + cB2*cB2*B2)*id2*id2, 0.f);
  const float un = fmaxf(sqrtf(U2), EPSF);
  const float lsc = artanh_c(un)/un;
  const float t1el = (cA1*(alpha*a) + cB1*y)*id1;
  const float uel  = (cA2*t1el + cB2*bv)*id2;
  return sigmoidf_(lsc*uel);
}

// ---- transpose weight_ih [1536][512] -> WihT [512][1536]
__global__ void k_prep_ih(const float* __restrict__ Wih, float* __restrict__ WihT){
  int i = blockIdx.x * blockDim.x + threadIdx.x;
  if (i >= H_ * G3_) return;
  int k = i / G3_, n = i % G3_;
  WihT[i] = Wih[n * H_ + k];
}

__device__ __forceinline__ uint4 pack8h(const float* s){
  __half2 p0 = __halves2half2(__float2half_rn(s[0]), __float2half_rn(s[1]));
  __half2 p1 = __halves2half2(__float2half_rn(s[2]), __float2half_rn(s[3]));
  __half2 p2 = __halves2half2(__float2half_rn(s[4]), __float2half_rn(s[5]));
  __half2 p3 = __halves2half2(__float2half_rn(s[6]), __float2half_rn(s[7]));
  uint4 r;
  r.x = __builtin_bit_cast(unsigned int, p0);
  r.y = __builtin_bit_cast(unsigned int, p1);
  r.z = __builtin_bit_cast(unsigned int, p2);
  r.w = __builtin_bit_cast(unsigned int, p3);
  return r;
}

// ---- weight_hh -> k-split register layout (f16, 8-k-wide uint4)
// WR[w][g][i][tid]: WG-slice w (k in [128w,128w+128)), gate g (0=z row 1024+tid,
// 1=r row tid, 2=cand row 512+tid), i<16 selects k0 = 128w + 8i.
__global__ void k_prep_hhR(const float* __restrict__ Whh, uint4* __restrict__ WR){
  int i = blockIdx.x * blockDim.x + threadIdx.x;   // 98304 total
  if (i >= 98304) return;
  int w = i / 24576, rem = i % 24576;
  int g = rem / 8192, rem2 = rem % 8192;
  int ii = rem2 >> 9, tid = rem2 & 511;
  int row = (g == 0) ? (1024 + tid) : ((g == 1) ? tid : (512 + tid));
  int k0 = w*128 + ii*8;
  WR[i] = pack8h(Whh + (size_t)row*H_ + k0);
}

// ---- tiled f32 GEMM: C[16384][1536] = A[16384][512] * Bt[512][1536]
__global__ __launch_bounds__(256) void k_gemm(const float* __restrict__ A,
                                              const float* __restrict__ Bt,
                                              float* __restrict__ C){
  const int N = G3_, K = H_;
  const int mbase = blockIdx.x * 64, nbase = blockIdx.y * 64;
  __shared__ float As[32][65];
  __shared__ float Bs[32][65];
  const int tid = threadIdx.x;
  const int tm = tid >> 4, tn = tid & 15;
  float acc[4][4] = {};
  for (int k0 = 0; k0 < K; k0 += 32){
    #pragma unroll
    for (int i = 0; i < 8; i++){
      int e = tid + 256*i;
      int m = e >> 5, k = e & 31;
      As[k][m] = A[(size_t)(mbase + m) * K + k0 + k];
      int kk = e >> 6, n = e & 63;
      Bs[kk][n] = Bt[(size_t)(k0 + kk) * N + nbase + n];
    }
    __syncthreads();
    #pragma unroll
    for (int kk = 0; kk < 32; kk++){
      float av[4], bv[4];
      #pragma unroll
      for (int i = 0; i < 4; i++) av[i] = As[kk][tm*4+i];
      #pragma unroll
      for (int j = 0; j < 4; j++) bv[j] = Bs[kk][tn*4+j];
      #pragma unroll
      for (int i = 0; i < 4; i++)
        #pragma unroll
        for (int j = 0; j < 4; j++)
          acc[i][j] = fmaf(av[i], bv[j], acc[i][j]);
    }
    __syncthreads();
  }
  #pragma unroll
  for (int i = 0; i < 4; i++)
    #pragma unroll
    for (int j = 0; j < 4; j++)
      C[(size_t)(mbase + tm*4 + i) * N + nbase + tn*4 + j] = acc[i][j];
}

// ---- mobius_matvec tail on Ux rows
__global__ void k_nonlin(const float* __restrict__ X, float* __restrict__ D){
  const int row = blockIdx.x;
  const int lane = threadIdx.x;
  const float* x = X + (size_t)row * H_;
  float s = 0.0f;
  for (int k = lane; k < H_; k += 64){ float v = x[k]; s = fmaf(v, v, s); }
  #pragma unroll
  for (int off = 32; off > 0; off >>= 1) s += __shfl_xor(s, off);
  const float xn = fmaxf(sqrtf(s), EPSF);
  const float art = artanh_c(xn);
  float* drow = D + (size_t)row * G3_;
  for (int g = 0; g < 3; g++){
    float* mx = drow + g * H_;
    float s2 = 0.0f;
    for (int k = lane; k < H_; k += 64){ float v = mx[k]; s2 = fmaf(v, v, s2); }
    #pragma unroll
    for (int off = 32; off > 0; off >>= 1) s2 += __shfl_xor(s2, off);
    const float raw = sqrtf(s2);
    const float mn = fmaxf(raw, EPSF);
    const float scale = (raw <= EPSF) ? 0.0f : (tanhf(mn / xn * art) / mn);
    for (int k = lane; k < H_; k += 64) mx[k] *= scale;
  }
}

// ---- scan: 4 WGs/row, k-split, 2 remote rounds + 5 barriers per step
__global__ __launch_bounds__(512, 2) void k_scan(
    const float* __restrict__ D,        // Ux' [T*B][1536]: r|c|z col blocks
    const uint4* __restrict__ WR,       // [4][3][16][512]
    const float* __restrict__ bias,     // [3][512] = b_r, b_c, b_z
    const float* __restrict__ h0,
    float* __restrict__ outbuf,         // [T][64][512]
    float* __restrict__ hlast,
    unsigned long long* __restrict__ PA,    // [64][4][2][512]
    unsigned long long* __restrict__ PB,    // [64][4][512]
    unsigned tagbase)
{
  const int blk = blockIdx.x;
  const int b = blk & 63, w = blk >> 6;
  const int tid = threadIdx.x;
  __shared__ __align__(16) __half hh[H_];
  __shared__ __align__(16) __half wvh[H_];
  __shared__ __align__(16) float red[120];
  __shared__ __align__(16) float redW[8];
  __shared__ __align__(16) float redS3[32];
  __shared__ __align__(16) float redS4[24];

  unsigned long long* paRow = PA + (size_t)b*4096;
  unsigned long long* pbRow = PB + (size_t)b*2048;

  // ---- preload this WG's k-slice of Whh into registers
  const uint4* wbase = WR + (size_t)w*24576 + tid;
  uint4 wZ[16], wRr[16], wC[16];
  #pragma unroll
  for (int i = 0; i < 16; i++) wZ[i]  = wbase[i*512];
  #pragma unroll
  for (int i = 0; i < 16; i++) wRr[i] = wbase[(16+i)*512];
  #pragma unroll
  for (int i = 0; i < 16; i++) wC[i]  = wbase[(32+i)*512];

  // own h element lives in a register; f16 copy of full h in LDS
  float h_own = h0[b*H_ + tid];
  hh[tid] = __float2half_rn(h_own);

  const float bz = bias[1024+tid], br = bias[tid], bc = bias[512+tid];
  {
    float vb[3] = { bz*bz, br*br, bc*bc };
    wave_reduce_store<3>(vb, red, tid);
  }
  __syncthreads();
  const float B2z = sum8(red), B2r = sum8(red+8), BC2 = sum8(red+16);
  __syncthreads();   // protect red before loop writes

  const uint4* hh4 = (const uint4*)hh;
  const uint4* wv4 = (const uint4*)wvh;
  const float* Dbase = D + (size_t)b * G3_;

  const int wp1 = (w+1)&3, wp2 = (w+2)&3, wp3 = (w+3)&3;
  unsigned long long* ownA0 = paRow + (w*2+0)*512 + tid;
  unsigned long long* ownA1 = paRow + (w*2+1)*512 + tid;
  unsigned long long* ownB  = pbRow + w*512 + tid;
  const unsigned long long* qa0 = paRow + (wp1*2+0)*512 + tid;
  const unsigned long long* qa1 = paRow + (wp1*2+1)*512 + tid;
  const unsigned long long* qa2 = paRow + (wp2*2+0)*512 + tid;
  const unsigned long long* qa3 = paRow + (wp2*2+1)*512 + tid;
  const unsigned long long* qa4 = paRow + (wp3*2+0)*512 + tid;
  const unsigned long long* qa5 = paRow + (wp3*2+1)*512 + tid;
  const unsigned long long* qb0 = pbRow + wp1*512 + tid;
  const unsigned long long* qb1 = pbRow + wp2*512 + tid;
  const unsigned long long* qb2 = pbRow + wp3*512 + tid;

  for (int t = 0; t < T_; t++){
    const unsigned tag = tagbase + (unsigned)t + 1u;
    const float* U = Dbase + (size_t)t * (B_ * G3_);
    const float yr = U[tid], yc = U[512 + tid], yz = U[1024 + tid];

    // ---- phase A: partial dots over own k-slice (z and r rows = column tid)
    float apz = 0.f, apr = 0.f;
    #pragma unroll
    for (int i = 0; i < 16; i++){
      const uint4 hp = hh4[(w<<4) + i];
      const uint4 z = wZ[i];
      apz = fdot2_(z.x, hp.x, apz); apz = fdot2_(z.y, hp.y, apz);
      apz = fdot2_(z.z, hp.z, apz); apz = fdot2_(z.w, hp.w, apz);
      const uint4 r = wRr[i];
      apr = fdot2_(r.x, hp.x, apr); apr = fdot2_(r.y, hp.y, apr);
      apr = fdot2_(r.z, hp.z, apr); apr = fdot2_(r.w, hp.w, apr);
    }
    postf(ownA0, apz, tag);
    postf(ownA1, apr, tag);

    // poll-independent stats (hide under remote wait)
    {
      float v[9] = { h_own*h_own, yz*yz, yz*bz, yr*yr, yr*br,
                     yc*yc, yc*bc, h_own*yc, h_own*bc };
      wave_reduce_store<9>(v, red, tid);
    }

    // ---- PA poll sweep: 3 remote WGs x 2 gates, overlapped loads
    float az = apz, ar = apr;
    {
      float f0=0.f,f1=0.f,f2=0.f,f3=0.f,f4=0.f,f5=0.f;
      unsigned pend = 0x3fu;
      do {
        unsigned long long u;
        if (pend & 1u ){ u = __hip_atomic_load(qa0, __ATOMIC_RELAXED, SCOPE_AGENT);
          if ((unsigned)(u>>32)==tag){ f0=__uint_as_float((unsigned)u); pend&=~1u; } }
        if (pend & 2u ){ u = __hip_atomic_load(qa1, __ATOMIC_RELAXED, SCOPE_AGENT);
          if ((unsigned)(u>>32)==tag){ f1=__uint_as_float((unsigned)u); pend&=~2u; } }
        if (pend & 4u ){ u = __hip_atomic_load(qa2, __ATOMIC_RELAXED, SCOPE_AGENT);
          if ((unsigned)(u>>32)==tag){ f2=__uint_as_float((unsigned)u); pend&=~4u; } }
        if (pend & 8u ){ u = __hip_atomic_load(qa3, __ATOMIC_RELAXED, SCOPE_AGENT);
          if ((unsigned)(u>>32)==tag){ f3=__uint_as_float((unsigned)u); pend&=~8u; } }
        if (pend & 16u){ u = __hip_atomic_load(qa4, __ATOMIC_RELAXED, SCOPE_AGENT);
          if ((unsigned)(u>>32)==tag){ f4=__uint_as_float((unsigned)u); pend&=~16u; } }
        if (pend & 32u){ u = __hip_atomic_load(qa5, __ATOMIC_RELAXED, SCOPE_AGENT);
          if ((unsigned)(u>>32)==tag){ f5=__uint_as_float((unsigned)u); pend&=~32u; } }
      } while (pend);
      az += f0 + f2 + f4;
      ar += f1 + f3 + f5;
    }
    // poll-dependent stats
    {
      float v[6] = { az*az, az*yz, az*bz, ar*ar, ar*yr, ar*br };
      wave_reduce_store<6>(v, red + 72, tid);
    }
    __syncthreads();                                   // BAR A
    const float H2  = sum8(red);
    const float Y2z = sum8(red+8),  YBz = sum8(red+16);
    const float Y2r = sum8(red+24), YBr = sum8(red+32);
    const float Y2c = sum8(red+40), YBc = sum8(red+48);
    const float HYd = sum8(red+56), HBd = sum8(red+64);
    const float A2z = sum8(red+72), AYz = sum8(red+80), ABz = sum8(red+88);
    const float A2r = sum8(red+96), AYr = sum8(red+104), ABr = sum8(red+112);

    const float xn = fmaxf(sqrtf(H2), EPSF);
    const float art_h = artanh_c(xn);
    const float zreg = gate_val(az, yz, bz, A2z, AYz, Y2z, ABz, YBz, B2z, xn, art_h);
    const float gr   = gate_val(ar, yr, br, A2r, AYr, Y2r, ABr, YBr, B2r, xn, art_h);
    const float wvv = gr * h_own;
    wvh[tid] = __float2half_rn(wvv);
    {
      float v1[1] = { wvv*wvv };
      wave_reduce_store<1>(v1, redW, tid);
    }
    __syncthreads();                                   // BAR B
    const float W2 = sum8(redW);
    const float wraw = sqrtf(W2);
    const float wn = fmaxf(wraw, EPSF);
    const float mu = (wraw <= EPSF) ? 0.f : (tanhf(wn/xn*art_h)/wn);
    const float rhn = fmaxf(mu*wraw, EPSF);

    // ---- phase B: candidate partial dot over own k-slice (row 512+tid)
    float cp = 0.f;
    #pragma unroll
    for (int i = 0; i < 16; i++){
      const uint4 rp = wv4[(w<<4) + i];
      const uint4 c = wC[i];
      cp = fdot2_(c.x, rp.x, cp); cp = fdot2_(c.y, rp.y, cp);
      cp = fdot2_(c.z, rp.z, cp); cp = fdot2_(c.w, rp.w, cp);
    }
    postf(ownB, cp, tag);
    float cdot = cp;
    {
      float g0=0.f,g1=0.f,g2=0.f;
      unsigned pend = 7u;
      do {
        unsigned long long u;
        if (pend & 1u){ u = __hip_atomic_load(qb0, __ATOMIC_RELAXED, SCOPE_AGENT);
          if ((unsigned)(u>>32)==tag){ g0=__uint_as_float((unsigned)u); pend&=~1u; } }
        if (pend & 2u){ u = __hip_atomic_load(qb1, __ATOMIC_RELAXED, SCOPE_AGENT);
          if ((unsigned)(u>>32)==tag){ g1=__uint_as_float((unsigned)u); pend&=~2u; } }
        if (pend & 4u){ u = __hip_atomic_load(qb2, __ATOMIC_RELAXED, SCOPE_AGENT);
          if ((unsigned)(u>>32)==tag){ g2=__uint_as_float((unsigned)u); pend&=~4u; } }
      } while (pend);
      cdot += g0 + g1 + g2;
    }
    const float cel = mu * cdot;
    const float hj = h_own;
    {
      float v[4] = { cel*cel, cel*yc, cel*bc, hj*cel };
      wave_reduce_store<4>(v, redS3, tid);
    }
    __syncthreads();                                   // BAR C
    const float C2 = sum8(redS3), CY = sum8(redS3+8),
                CB = sum8(redS3+16), HC = sum8(redS3+24);
    const float craw = sqrtf(C2);
    const float cmn2 = fmaxf(craw, EPSF);
    const float alc = (craw <= EPSF) ? 0.f : (tanhf(cmn2/rhn*artanh_c(rhn))/cmn2);
    const float X2c = alc*alc*C2, XYc = alc*CY, XBc = alc*CB, HXc = alc*HC;
    const float cA1c = 1.f + 2.f*XYc + Y2c, cB1c = 1.f - X2c;
    const float den1c = fmaxf(1.f + 2.f*XYc + X2c*Y2c, EPSF), id1c = 1.f/den1c;
    const float T2c = fmaxf((cA1c*cA1c*X2c + 2.f*cA1c*cB1c*XYc + cB1c*cB1c*Y2c)*id1c*id1c, 0.f);
    const float TBc = (cA1c*XBc + cB1c*YBc)*id1c;
    const float HT1 = (cA1c*HXc + cB1c*HYd)*id1c;
    const float cA2c = 1.f + 2.f*TBc + BC2, cB2c = 1.f - T2c;
    const float den2c = fmaxf(1.f + 2.f*TBc + T2c*BC2, EPSF), id2c = 1.f/den2c;
    const float HTL2 = fmaxf((cA2c*cA2c*T2c + 2.f*cA2c*cB2c*TBc + cB2c*cB2c*BC2)*id2c*id2c, 0.f);
    const float HHTL = (cA2c*HT1 + cB2c*HBd)*id2c;
    const float cAd = 1.f - 2.f*HHTL + HTL2, cBd = 1.f - H2;
    const float dend = fmaxf(1.f - 2.f*HHTL + H2*HTL2, EPSF), idd = 1.f/dend;
    const float t1cel = (cA1c*(alc*cel) + cB1c*yc)*id1c;
    const float htlel = (cA2c*t1cel + cB2c*bc)*id2c;
    const float del = (cAd*(-hj) + cBd*htlel)*idd;
    const float w2el = zreg*del;
    {
      float v[3] = { del*del, w2el*w2el, hj*w2el };
      wave_reduce_store<3>(v, redS4, tid);
    }
    __syncthreads();                                   // BAR D
    const float D2v = sum8(redS4), W22 = sum8(redS4+8), HW = sum8(redS4+16);
    const float dnv = fmaxf(sqrtf(D2v), EPSF);
    const float w2raw = sqrtf(W22);
    const float w2n = fmaxf(w2raw, EPSF);
    const float nu = (w2raw <= EPSF) ? 0.f : (tanhf(w2n/dnv*artanh_c(dnv))/w2n);
    const float Y2f = nu*nu*W22, XYf = nu*HW;
    const float cAf = 1.f + 2.f*XYf + Y2f, cBf = 1.f - H2;
    const float denf = fmaxf(1.f + 2.f*XYf + H2*Y2f, EPSF), idf = 1.f/denf;
    const float hnew = (cAf*hj + cBf*(nu*w2el))*idf;
    h_own = hnew;
    hh[tid] = __float2half_rn(hnew);
    if (w == 0){
      outbuf[(size_t)(t*B_ + b)*H_ + tid] = hnew;
      if (t == T_-1) hlast[b*H_ + tid] = hnew;
    }
    __syncthreads();                                   // BAR E
  }
}

extern "C" void kernel_launch(void* const* d_in, const int* in_sizes, int n_in,
                              void* d_out, int out_size, void* d_ws, size_t ws_size,
                              hipStream_t stream){
  (void)in_sizes; (void)n_in; (void)out_size; (void)ws_size;
  const float* input = (const float*)d_in[0];
  const float* h0    = (const float*)d_in[1];
  const float* wih1  = (const float*)d_in[2];
  const float* wih2  = (const float*)d_in[3];
  const float* whh1  = (const float*)d_in[4];
  const float* whh2  = (const float*)d_in[5];
  const float* bias1 = (const float*)d_in[6];
  const float* bias2 = (const float*)d_in[7];
  float* out = (float*)d_out;

  // ws (floats): WihT 786432 | Dbuf 25165824 | WR 393216 |
  //              PA 524288 (262144 u64) | PB 262144 (131072 u64)   (shared by layers)
  float* A_    = (float*)d_ws;
  float* Dbuf  = A_ + 786432;
  uint4* WR    = (uint4*)(Dbuf + 25165824);
  unsigned long long* PA = (unsigned long long*)(WR + 98304);
  unsigned long long* PB = PA + 262144;

  float* out1 = out;                          // staged; consumed before scan-2 overwrites
  float* ht   = out + (size_t)T_ * B_ * H_;

  // layer 1  (tags 1..256)
  k_prep_ih<<<3072, 256, 0, stream>>>(wih1, A_);
  k_gemm<<<dim3(256, 24), 256, 0, stream>>>(input, A_, Dbuf);
  k_nonlin<<<T_*B_, 64, 0, stream>>>(input, Dbuf);
  k_prep_hhR<<<384, 256, 0, stream>>>(whh1, WR);
  k_scan<<<256, 512, 0, stream>>>(Dbuf, WR, bias1, h0, out1, ht, PA, PB, 0u);

  // layer 2  (tags 257..512; every slot was rewritten by layer 1, so no aliasing)
  k_prep_ih<<<3072, 256, 0, stream>>>(wih2, A_);
  k_gemm<<<dim3(256, 24), 256, 0, stream>>>(out1, A_, Dbuf);
  k_nonlin<<<T_*B_, 64, 0, stream>>>(out1, Dbuf);
  k_prep_hhR<<<384, 256, 0, stream>>>(whh2, WR);
  k_scan<<<256, 512, 0, stream>>>(Dbuf, WR, bias2, h0 + B_*H_, out, ht + B_*H_, PA, PB, 256u);
}

// Round 2
// 7783.750 us; speedup vs baseline: 1.4234x; 1.4234x over previous
//
#include <hip/hip_runtime.h>
#include <hip/hip_fp16.h>
#include <math.h>
#include <stdint.h>

// MobiusGRU T=256 B=64 D=H=512, 2 layers.
// R9 = R7 (best verified: 3340us/scan) with ONE change: __launch_bounds__(512,2)
// -> (512,1). Grid is exactly 256 WGs on 256 CUs (1 block/CU regardless), so the
// old bound only capped VGPRs at 128 -- below the 192 VGPRs of declared weight
// slices (48 x uint4/thread), forcing the compiler to re-stream weights from L2
// every t-step (~98 MB/step across the chip). With a 256-VGPR budget the weight
// slices become truly register-resident. Comm structure unchanged from R7:
// 4 WGs/row, 5 fence-free tagged exchange rounds/step, relaxed agent atomics.

#define T_  256
#define B_  64
#define H_  512
#define G3_ 1536
#define EPSF 1e-15f
#define CLIPF (1.0f - 1e-5f)
#define SCOPE_AGENT __HIP_MEMORY_SCOPE_AGENT

typedef _Float16 v2h __attribute__((ext_vector_type(2)));

__device__ __forceinline__ float fdot2_(unsigned int w, unsigned int h, float c){
#if __has_builtin(__builtin_amdgcn_fdot2)
  return __builtin_amdgcn_fdot2(__builtin_bit_cast(v2h, w), __builtin_bit_cast(v2h, h), c, false);
#else
  const __half2 wh = __builtin_bit_cast(__half2, w);
  const __half2 hh = __builtin_bit_cast(__half2, h);
  return c + __low2float(wh)*__low2float(hh) + __high2float(wh)*__high2float(hh);
#endif
}

__device__ __forceinline__ float artanh_c(float x){
  x = fminf(fmaxf(x, -CLIPF), CLIPF);
  return 0.5f * logf((1.0f + x) / (1.0f - x));
}
__device__ __forceinline__ float sigmoidf_(float x){ return 1.0f/(1.0f+expf(-x)); }
__device__ __forceinline__ float hsum4(float4 v){ return (v.x+v.y)+(v.z+v.w); }

// fence-free tagged exchange (relaxed agent atomics: no cache inv/wb)
__device__ __forceinline__ void postf(unsigned long long* p, float x, unsigned tag){
  unsigned long long v = ((unsigned long long)tag << 32) |
                         (unsigned long long)__float_as_uint(x);
  __hip_atomic_store(p, v, __ATOMIC_RELAXED, SCOPE_AGENT);
}
__device__ __forceinline__ float pollf(const unsigned long long* p, unsigned tag){
  unsigned long long v = __hip_atomic_load(p, __ATOMIC_RELAXED, SCOPE_AGENT);
  while ((unsigned)(v >> 32) != tag)
    v = __hip_atomic_load(p, __ATOMIC_RELAXED, SCOPE_AGENT);
  return __uint_as_float((unsigned)v);
}

// reduce NS values across the wave; lane0 stores red[s*8 + wave] (8 waves)
template<int NS>
__device__ __forceinline__ void wave_reduce_store(float (&v)[NS], float* red, int tid){
  #pragma unroll
  for (int off = 32; off > 0; off >>= 1)
    #pragma unroll
    for (int s = 0; s < NS; s++) v[s] += __shfl_xor(v[s], off);
  if ((tid & 63) == 0)
    #pragma unroll
    for (int s = 0; s < NS; s++) red[s*8 + (tid >> 6)] = v[s];
}

// ---- transpose weight_ih [1536][512] -> WihT [512][1536]
__global__ void k_prep_ih(const float* __restrict__ Wih, float* __restrict__ WihT){
  int i = blockIdx.x * blockDim.x + threadIdx.x;
  if (i >= H_ * G3_) return;
  int k = i / G3_, n = i % G3_;
  WihT[i] = Wih[n * H_ + k];
}

__device__ __forceinline__ uint4 pack8h(const float* s){
  __half2 p0 = __halves2half2(__float2half_rn(s[0]), __float2half_rn(s[1]));
  __half2 p1 = __halves2half2(__float2half_rn(s[2]), __float2half_rn(s[3]));
  __half2 p2 = __halves2half2(__float2half_rn(s[4]), __float2half_rn(s[5]));
  __half2 p3 = __halves2half2(__float2half_rn(s[6]), __float2half_rn(s[7]));
  uint4 r;
  r.x = __builtin_bit_cast(unsigned int, p0);
  r.y = __builtin_bit_cast(unsigned int, p1);
  r.z = __builtin_bit_cast(unsigned int, p2);
  r.w = __builtin_bit_cast(unsigned int, p3);
  return r;
}

// ---- weight_hh -> register-resident layouts (f16, 8-k-wide uint4)
// WzrR[w][i<32][tid<512]: thread tid=(ks<<8)|c owns col j=128w+(c&127)
//   (c<128: z row=1024+j, else r row=j), k0 = ks*256 + i*8
// WhcR[w][q<4][i<16][c<128]: cand col j=128w+c (row 512+j), k0 = q*128 + i*8
__global__ void k_prep_hhR(const float* __restrict__ Whh, uint4* __restrict__ WzrR,
                           uint4* __restrict__ WhcR){
  int i = blockIdx.x * blockDim.x + threadIdx.x;   // 98304 total
  if (i < 65536){
    int w = i >> 14, rem = i & 16383;
    int ii = rem >> 9, tid = rem & 511;
    int c = tid & 255, ks = tid >> 8;
    int j = 128*w + (c & 127);
    int row = (c < 128) ? (1024 + j) : j;
    int k0 = ks*256 + ii*8;
    WzrR[i] = pack8h(Whh + row*H_ + k0);
  } else {
    int e = i - 65536;                              // 32768
    int w = e >> 13, rem = e & 8191;
    int q = rem >> 11, rem2 = rem & 2047;
    int ii = rem2 >> 7, c = rem2 & 127;
    int row = 512 + 128*w + c;
    int k0 = q*128 + ii*8;
    WhcR[e] = pack8h(Whh + row*H_ + k0);
  }
}

// ---- tiled f32 GEMM: C[16384][1536] = A[16384][512] * Bt[512][1536]
__global__ __launch_bounds__(256) void k_gemm(const float* __restrict__ A,
                                              const float* __restrict__ Bt,
                                              float* __restrict__ C){
  const int N = G3_, K = H_;
  const int mbase = blockIdx.x * 64, nbase = blockIdx.y * 64;
  __shared__ float As[32][65];
  __shared__ float Bs[32][65];
  const int tid = threadIdx.x;
  const int tm = tid >> 4, tn = tid & 15;
  float acc[4][4] = {};
  for (int k0 = 0; k0 < K; k0 += 32){
    #pragma unroll
    for (int i = 0; i < 8; i++){
      int e = tid + 256*i;
      int m = e >> 5, k = e & 31;
      As[k][m] = A[(size_t)(mbase + m) * K + k0 + k];
      int kk = e >> 6, n = e & 63;
      Bs[kk][n] = Bt[(size_t)(k0 + kk) * N + nbase + n];
    }
    __syncthreads();
    #pragma unroll
    for (int kk = 0; kk < 32; kk++){
      float av[4], bv[4];
      #pragma unroll
      for (int i = 0; i < 4; i++) av[i] = As[kk][tm*4+i];
      #pragma unroll
      for (int j = 0; j < 4; j++) bv[j] = Bs[kk][tn*4+j];
      #pragma unroll
      for (int i = 0; i < 4; i++)
        #pragma unroll
        for (int j = 0; j < 4; j++)
          acc[i][j] = fmaf(av[i], bv[j], acc[i][j]);
    }
    __syncthreads();
  }
  #pragma unroll
  for (int i = 0; i < 4; i++)
    #pragma unroll
    for (int j = 0; j < 4; j++)
      C[(size_t)(mbase + tm*4 + i) * N + nbase + tn*4 + j] = acc[i][j];
}

// ---- mobius_matvec tail on Ux rows
__global__ void k_nonlin(const float* __restrict__ X, float* __restrict__ D){
  const int row = blockIdx.x;
  const int lane = threadIdx.x;
  const float* x = X + (size_t)row * H_;
  float s = 0.0f;
  for (int k = lane; k < H_; k += 64){ float v = x[k]; s = fmaf(v, v, s); }
  #pragma unroll
  for (int off = 32; off > 0; off >>= 1) s += __shfl_xor(s, off);
  const float xn = fmaxf(sqrtf(s), EPSF);
  const float art = artanh_c(xn);
  float* drow = D + (size_t)row * G3_;
  for (int g = 0; g < 3; g++){
    float* mx = drow + g * H_;
    float s2 = 0.0f;
    for (int k = lane; k < H_; k += 64){ float v = mx[k]; s2 = fmaf(v, v, s2); }
    #pragma unroll
    for (int off = 32; off > 0; off >>= 1) s2 += __shfl_xor(s2, off);
    const float raw = sqrtf(s2);
    const float mn = fmaxf(raw, EPSF);
    const float scale = (raw <= EPSF) ? 0.0f : (tanhf(mn / xn * art) / mn);
    for (int k = lane; k < H_; k += 64) mx[k] *= scale;
  }
}

// ---- scan: 4 WGs/row (256 WGs x 512 thr), weights in VGPRs, fence-free sync
__global__ __launch_bounds__(512, 1) void k_scan(
    const float* __restrict__ D,        // Ux' [T*B][1536]: r|c|z col blocks
    const uint4* __restrict__ WzrR,     // [4][32][512]
    const uint4* __restrict__ WhcR,     // [4][4][16][128]
    const float* __restrict__ bias,     // [3][512] = b_r, b_c, b_z
    const float* __restrict__ h0,
    float* __restrict__ outbuf,         // [T][64][512]
    float* __restrict__ hlast,
    unsigned long long* __restrict__ hS,    // [64][512]
    unsigned long long* __restrict__ wvS,   // [64][512]
    unsigned long long* __restrict__ S1s,   // [64][4][16]
    unsigned long long* __restrict__ S3s,   // [64][4][16]
    unsigned long long* __restrict__ S4s)   // [64][4][16]
{
  const int blk = blockIdx.x;
  const int b = blk & 63, w = blk >> 6;
  const int tid = threadIdx.x;
  const int lane = tid & 63, wave = tid >> 6;
  __shared__ __align__(16) __half hh[H_];
  __shared__ __align__(16) float hf[H_];
  __shared__ __align__(16) __half wvh[H_];
  __shared__ __align__(16) float ph[512];
  __shared__ __align__(16) float red[96];
  __shared__ __align__(16) float redW[8];
  __shared__ __align__(16) float xr[16];

  unsigned long long* hRow  = hS  + b*512;
  unsigned long long* wvRow = wvS + b*512;
  unsigned long long* s1Row = S1s + b*64;
  unsigned long long* s3Row = S3s + b*64;
  unsigned long long* s4Row = S4s + b*64;

  // ---- preload weight slices into registers
  const int ks = tid >> 8;                      // phase A k-half
  const int c2 = tid & 127, q = tid >> 7;       // phase B: col + k-quarter
  const uint4* wAb = WzrR + (size_t)w*32*512 + tid;
  const uint4* wBb = WhcR + ((size_t)(w*4 + q)*16)*128 + c2;
  uint4 wA[32];
  #pragma unroll
  for (int i = 0; i < 32; i++) wA[i] = wAb[i*512];
  uint4 wB[16];
  #pragma unroll
  for (int i = 0; i < 16; i++) wB[i] = wBb[i*128];

  // initial h
  {
    const float hv0 = h0[b*H_ + tid];
    hf[tid] = hv0;
    hh[tid] = __float2half_rn(hv0);
  }
  // bias values + (local) bias norms
  const int jg = 128*w + (tid & 127);           // gate/cand col for tid<256 / tid<128
  const bool isZ = (tid < 128);
  const bool isGate = (tid < 256);
  const float bval = isGate ? (isZ ? bias[1024 + jg] : bias[jg]) : 0.f;
  const float bcj  = isZ ? bias[512 + jg] : 0.f;
  float B2own, BC2;
  {
    const float vz = bias[1024 + tid], vr = bias[tid], vc = bias[512 + tid];
    float vb[3] = { vz*vz, vr*vr, vc*vc };
    wave_reduce_store<3>(vb, red, tid);
    __syncthreads();
    const float4* p = (const float4*)red;
    const float B2z = hsum4(p[0]) + hsum4(p[1]);
    const float B2r = hsum4(p[2]) + hsum4(p[3]);
    BC2 = hsum4(p[4]) + hsum4(p[5]);
    B2own = isZ ? B2z : B2r;
    __syncthreads();
  }

  const uint4* hh4 = (const uint4*)hh;
  const uint4* wv4 = (const uint4*)wvh;
  const float* Dbase = D + (size_t)b * G3_;

  float zreg = 0.f;
  for (int t = 0; t < T_; t++){
    const unsigned tag = (unsigned)(t + 1);
    const float* U = Dbase + (size_t)t * (B_ * G3_);
    // Ux loads issue early
    const float yg = isGate ? U[(isZ ? 1024 : 0) + jg] : 0.f;
    const float yc = isZ ? U[512 + jg] : 0.f;

    // ---- h gather (posted with tag t by step t-1)
    if (t > 0){
      const float hv = pollf(hRow + tid, (unsigned)t);
      hf[tid] = hv;
      hh[tid] = __float2half_rn(hv);
    }
    __syncthreads();                                   // bar1
    const float hv = hf[tid];

    // ---- phase A: register x LDS-broadcast dot (col tid&255, k-half ks)
    float ap = 0.f;
    #pragma unroll
    for (int i = 0; i < 32; i++){
      const uint4 wr = wA[i];
      const uint4 hp = hh4[ks*32 + i];
      ap = fdot2_(wr.x, hp.x, ap);
      ap = fdot2_(wr.y, hp.y, ap);
      ap = fdot2_(wr.z, hp.z, ap);
      ap = fdot2_(wr.w, hp.w, ap);
    }
    ph[tid] = ap;
    __syncthreads();                                   // bar2
    const float a = isGate ? (ph[tid] + ph[tid + 256]) : 0.f;

    // ---- S1: local 11-slot reduce (slot0=h2 local-only; 10 gate dots exchanged)
    {
      float v[11];
      v[0] = hv*hv;
      #pragma unroll
      for (int s = 1; s < 11; s++) v[s] = 0.f;
      if (isGate){
        const int o = isZ ? 1 : 6;
        v[o] = a*a; v[o+1] = a*yg; v[o+2] = yg*yg; v[o+3] = a*bval; v[o+4] = yg*bval;
      }
      wave_reduce_store<11>(v, red, tid);
    }
    __syncthreads();                                   // bar3
    float H2;
    { const float4* p = (const float4*)red; H2 = hsum4(p[0]) + hsum4(p[1]); }
    if (wave == 0 && lane < 10){
      float s = 0.f;
      const float* r = red + (1 + lane)*8;
      #pragma unroll
      for (int i = 0; i < 8; i++) s += r[i];
      postf(s1Row + w*16 + lane, s, tag);
    }
    if (wave == 0){
      const int wgi = lane >> 4, s = lane & 15;
      float v = (s < 10) ? pollf(s1Row + wgi*16 + s, tag) : 0.f;
      v += __shfl_xor(v, 16);
      v += __shfl_xor(v, 32);
      if (lane < 16) xr[lane] = v;
    }
    __syncthreads();                                   // bar4

    // ---- gate math (threads 0..255)
    const float xn = fmaxf(sqrtf(H2), EPSF);
    const float art_h = artanh_c(xn);
    if (isGate){
      const int o = isZ ? 0 : 5;
      const float A2 = xr[o], AY = xr[o+1], Yy2 = xr[o+2], AB = xr[o+3], YB = xr[o+4];
      const float mraw = sqrtf(A2);
      const float mnc = fmaxf(mraw, EPSF);
      const float alpha = (mraw <= EPSF) ? 0.f : (tanhf(mnc/xn*art_h)/mnc);
      const float X2 = alpha*alpha*A2, XY = alpha*AY, XB = alpha*AB;
      const float cA1 = 1.f + 2.f*XY + Yy2, cB1 = 1.f - X2;
      const float den1 = fmaxf(1.f + 2.f*XY + X2*Yy2, EPSF), id1 = 1.f/den1;
      const float T2 = fmaxf((cA1*cA1*X2 + 2.f*cA1*cB1*XY + cB1*cB1*Yy2)*id1*id1, 0.f);
      const float TB = (cA1*XB + cB1*YB)*id1;
      const float cA2 = 1.f + 2.f*TB + B2own, cB2 = 1.f - T2;
      const float den2 = fmaxf(1.f + 2.f*TB + T2*B2own, EPSF), id2 = 1.f/den2;
      const float U2 = fmaxf((cA2*cA2*T2 + 2.f*cA2*cB2*TB + cB2*cB2*B2own)*id2*id2, 0.f);
      const float un = fmaxf(sqrtf(U2), EPSF);
      const float lsc = artanh_c(un)/un;
      const float t1el = (cA1*(alpha*a) + cB1*yg)*id1;
      const float uel  = (cA2*t1el + cB2*bval)*id2;
      const float g = sigmoidf_(lsc*uel);
      if (isZ) zreg = g;
      else postf(wvRow + jg, g * hf[jg], tag);
    }
    // ---- wv gather + local W2 reduce
    const float wvv = pollf(wvRow + tid, tag);
    wvh[tid] = __float2half_rn(wvv);
    {
      float v1[1] = { wvv*wvv };
      wave_reduce_store<1>(v1, redW, tid);
    }
    __syncthreads();                                   // bar5
    float W2;
    { const float4* p = (const float4*)redW; W2 = hsum4(p[0]) + hsum4(p[1]); }
    const float wraw = sqrtf(W2);
    const float wn = fmaxf(wraw, EPSF);
    const float mu = (wraw <= EPSF) ? 0.f : (tanhf(wn/xn*art_h)/wn);
    const float rhn = fmaxf(mu*wraw, EPSF);

    // ---- phase B: register x LDS-broadcast dot (col c2, k-quarter q)
    float cp = 0.f;
    #pragma unroll
    for (int i = 0; i < 16; i++){
      const uint4 wr = wB[i];
      const uint4 rp = wv4[q*16 + i];
      cp = fdot2_(wr.x, rp.x, cp);
      cp = fdot2_(wr.y, rp.y, cp);
      cp = fdot2_(wr.z, rp.z, cp);
      cp = fdot2_(wr.w, rp.w, cp);
    }
    ph[tid] = cp;
    __syncthreads();                                   // bar6
    float cel = 0.f, hj = 0.f;
    if (isZ){
      cel = mu * (ph[tid] + ph[tid+128] + ph[tid+256] + ph[tid+384]);
      hj  = hf[jg];
    }
    // ---- S3: 8 candidate dots
    {
      float v[8] = { cel*cel, cel*yc, yc*yc, cel*bcj, yc*bcj, hj*cel, hj*yc, hj*bcj };
      wave_reduce_store<8>(v, red, tid);
    }
    __syncthreads();                                   // bar7
    if (wave == 0 && lane < 8){
      float s = 0.f;
      const float* r = red + lane*8;
      #pragma unroll
      for (int i = 0; i < 8; i++) s += r[i];
      postf(s3Row + w*16 + lane, s, tag);
    }
    if (wave == 0){
      const int wgi = lane >> 4, s = lane & 15;
      float v = (s < 8) ? pollf(s3Row + wgi*16 + s, tag) : 0.f;
      v += __shfl_xor(v, 16);
      v += __shfl_xor(v, 32);
      if (lane < 16) xr[lane] = v;
    }
    __syncthreads();                                   // bar8
    const float C2 = xr[0], CY = xr[1], Y2c = xr[2], CB = xr[3],
                YBc = xr[4], HC = xr[5], HYd = xr[6], HBd = xr[7];
    const float craw = sqrtf(C2);
    const float cmn2 = fmaxf(craw, EPSF);
    const float alc = (craw <= EPSF) ? 0.f : (tanhf(cmn2/rhn*artanh_c(rhn))/cmn2);
    const float X2c = alc*alc*C2, XYc = alc*CY, XBc = alc*CB, HXc = alc*HC;
    const float cA1c = 1.f + 2.f*XYc + Y2c, cB1c = 1.f - X2c;
    const float den1c = fmaxf(1.f + 2.f*XYc + X2c*Y2c, EPSF), id1c = 1.f/den1c;
    const float T2c = fmaxf((cA1c*cA1c*X2c + 2.f*cA1c*cB1c*XYc + cB1c*cB1c*Y2c)*id1c*id1c, 0.f);
    const float TBc = (cA1c*XBc + cB1c*YBc)*id1c;
    const float HT1 = (cA1c*HXc + cB1c*HYd)*id1c;
    const float cA2c = 1.f + 2.f*TBc + BC2, cB2c = 1.f - T2c;
    const float den2c = fmaxf(1.f + 2.f*TBc + T2c*BC2, EPSF), id2c = 1.f/den2c;
    const float HTL2 = fmaxf((cA2c*cA2c*T2c + 2.f*cA2c*cB2c*TBc + cB2c*cB2c*BC2)*id2c*id2c, 0.f);
    const float HHTL = (cA2c*HT1 + cB2c*HBd)*id2c;
    const float cAd = 1.f - 2.f*HHTL + HTL2, cBd = 1.f - H2;
    const float dend = fmaxf(1.f - 2.f*HHTL + H2*HTL2, EPSF), idd = 1.f/dend;
    float del = 0.f, w2el = 0.f;
    if (isZ){
      const float t1cel = (cA1c*(alc*cel) + cB1c*yc)*id1c;
      const float htlel = (cA2c*t1cel + cB2c*bcj)*id2c;
      del = (cAd*(-hj) + cBd*htlel)*idd;
      w2el = zreg*del;
    }
    // ---- S4: {d2, |z.*d|2, h.(z.*d)}
    {
      float v[3] = { del*del, w2el*w2el, hj*w2el };
      wave_reduce_store<3>(v, red, tid);
    }
    __syncthreads();                                   // bar9
    if (wave == 0 && lane < 3){
      float s = 0.f;
      const float* r = red + lane*8;
      #pragma unroll
      for (int i = 0; i < 8; i++) s += r[i];
      postf(s4Row + w*16 + lane, s, tag);
    }
    if (wave == 0){
      const int wgi = lane >> 4, s = lane & 15;
      float v = (s < 3) ? pollf(s4Row + wgi*16 + s, tag) : 0.f;
      v += __shfl_xor(v, 16);
      v += __shfl_xor(v, 32);
      if (lane < 16) xr[lane] = v;
    }
    __syncthreads();                                   // bar10
    const float D2v = xr[0], W22 = xr[1], HW = xr[2];
    const float dnv = fmaxf(sqrtf(D2v), EPSF);
    const float w2raw = sqrtf(W22);
    const float w2n = fmaxf(w2raw, EPSF);
    const float nu = (w2raw <= EPSF) ? 0.f : (tanhf(w2n/dnv*artanh_c(dnv))/w2n);
    const float Y2f = nu*nu*W22, XYf = nu*HW;
    const float cAf = 1.f + 2.f*XYf + Y2f, cBf = 1.f - H2;
    const float denf = fmaxf(1.f + 2.f*XYf + H2*Y2f, EPSF), idf = 1.f/denf;
    if (isZ){
      const float hnew = (cAf*hj + cBf*(nu*w2el))*idf;
      outbuf[(size_t)(t*B_ + b)*H_ + jg] = hnew;
      postf(hRow + jg, hnew, tag);         // tag t+1, polled by step t+1
      if (t == T_-1) hlast[b*H_ + jg] = hnew;
    }
  }
}

extern "C" void kernel_launch(void* const* d_in, const int* in_sizes, int n_in,
                              void* d_out, int out_size, void* d_ws, size_t ws_size,
                              hipStream_t stream){
  (void)in_sizes; (void)n_in; (void)out_size; (void)ws_size;
  const float* input = (const float*)d_in[0];
  const float* h0    = (const float*)d_in[1];
  const float* wih1  = (const float*)d_in[2];
  const float* wih2  = (const float*)d_in[3];
  const float* whh1  = (const float*)d_in[4];
  const float* whh2  = (const float*)d_in[5];
  const float* bias1 = (const float*)d_in[6];
  const float* bias2 = (const float*)d_in[7];
  float* out = (float*)d_out;

  // ws (floats): WihT 786432 | Dbuf 25165824 | WzrR 262144 | WhcR 131072
  //              per-layer comm x2: hS 65536 | wvS 65536 | S1 8192 | S3 8192 | S4 8192
  float* A_    = (float*)d_ws;
  float* Dbuf  = A_ + 786432;
  uint4* WzrR  = (uint4*)(Dbuf + 25165824);
  uint4* WhcR  = WzrR + 65536;
  float* comm0 = (float*)(WhcR + 32768);
  unsigned long long* hS1  = (unsigned long long*)comm0;
  unsigned long long* wvS1 = hS1  + 32768;
  unsigned long long* S1a  = wvS1 + 32768;
  unsigned long long* S3a  = S1a  + 4096;
  unsigned long long* S4a  = S3a  + 4096;
  unsigned long long* hS2  = S4a  + 4096;
  unsigned long long* wvS2 = hS2  + 32768;
  unsigned long long* S1b  = wvS2 + 32768;
  unsigned long long* S3b  = S1b  + 4096;
  unsigned long long* S4b  = S3b  + 4096;

  float* out1 = out;                          // staged; consumed before scan-2 overwrites
  float* ht   = out + (size_t)T_ * B_ * H_;

  // layer 1
  k_prep_ih<<<3072, 256, 0, stream>>>(wih1, A_);
  k_gemm<<<dim3(256, 24), 256, 0, stream>>>(input, A_, Dbuf);
  k_nonlin<<<T_*B_, 64, 0, stream>>>(input, Dbuf);
  k_prep_hhR<<<384, 256, 0, stream>>>(whh1, WzrR, WhcR);
  k_scan<<<256, 512, 0, stream>>>(Dbuf, WzrR, WhcR, bias1, h0, out1, ht,
                                  hS1, wvS1, S1a, S3a, S4a);

  // layer 2
  k_prep_ih<<<3072, 256, 0, stream>>>(wih2, A_);
  k_gemm<<<dim3(256, 24), 256, 0, stream>>>(out1, A_, Dbuf);
  k_nonlin<<<T_*B_, 64, 0, stream>>>(out1, Dbuf);
  k_prep_hhR<<<384, 256, 0, stream>>>(whh2, WzrR, WhcR);
  k_scan<<<256, 512, 0, stream>>>(Dbuf, WzrR, WhcR, bias2, h0 + B_*H_, out, ht + B_*H_,
                                  hS2, wvS2, S1b, S3b, S4b);
}